// Round 1
// baseline (103.555 us; speedup 1.0000x reference)
//
#include <hip/hip_runtime.h>
#include <stdint.h>
#include <stddef.h>

// Problem constants: B=16, H=8, N=256, D=32
constexpr int Bc = 16, Hc = 8, Nc = 256, Dc = 32;
constexpr float LOG2E = 1.44269504088896340736f;

// score_ij = sum_d a_d * silu(q_id + k_jd); silu(x) = x/2 + G(x),
// G(x)=(x/2)tanh(x/2) even. Fit G ~ sum_m c_m cos(m*pi*x/PHALF) (constexpr LS);
// cos(w(q+k)) separates -> f16 MFMA contraction. j-constant terms cancel in
// softmax; 0.5*Ak_j survives (exact fp32).
//
// R10: counters showed all pipes idle (Mfma 0.9%, VALU 2.4%, HBM 4%) at 97us
// -> latency-bound, not throughput-bound. Causes: (1) chained-rotation trig
// state (48 VGPRs) + acc(32) blew the 128-reg cap of launch_bounds(1024,4)
// -> spills inside the serial chunk chain; (2) exactly 1 fat 16-wave barrier
// domain per CU, no inter-block overlap. Fix: recompute features from phase
// r1=fract(x/2P) each chunk (20 state regs, trans pipe has headroom), and
// 512-thr blocks (64x256 tile) with 80KB LDS -> 2 independent blocks/CU.
constexpr int    MF    = 10;
constexpr double PHALF = 9.7;
constexpr double LFIT  = 9.0;

// ---------------- constexpr math (no hand-typed magic numbers) -------------
constexpr double PI_ = 3.14159265358979323846;

constexpr double cexp_(double x) {
    int n = (int)(x >= 0 ? x + 0.5 : x - 0.5);
    double f = x - n, t = 1.0, s = 1.0;
    for (int i = 1; i <= 26; ++i) { t *= f / i; s += t; }
    const double E = 2.71828182845904523536;
    double en = 1.0, bb = n >= 0 ? E : 1.0 / E;
    int an = n < 0 ? -n : n;
    for (int i = 0; i < an; ++i) en *= bb;
    return s * en;
}
constexpr double creduce_(double x) {
    while (x >  PI_) x -= 2.0 * PI_;
    while (x < -PI_) x += 2.0 * PI_;
    return x;
}
constexpr double ccos_(double x0) {
    double x = creduce_(x0), x2 = x * x, t = 1.0, s = 1.0;
    for (int i = 1; i <= 16; ++i) { t *= -x2 / ((2.0*i - 1.0) * (2.0*i)); s += t; }
    return s;
}
constexpr double csin_(double x0) {
    double x = creduce_(x0), x2 = x * x, t = x, s = x;
    for (int i = 1; i <= 16; ++i) { t *= -x2 / ((2.0*i) * (2.0*i + 1.0)); s += t; }
    return s;
}
constexpr double Gfun_(double x) {
    double z = x < 0 ? -x : x;
    double e = cexp_(z);
    return 0.5 * z * ((e - 1.0) / (e + 1.0));
}
constexpr double csqrt_(double x) {
    if (x <= 0) return 0;
    double r = x > 1 ? x : 1;
    for (int i = 0; i < 40; ++i) r = 0.5 * (r + x / r);
    return r;
}

struct FitT { float tk[MF + 1]; float tq[MF + 1]; };

constexpr FitT lsFit_() {
    constexpr int NB = MF + 1;
    double A[NB][NB] = {}, bv[NB] = {};
    for (int p = 0; p < NB; ++p)
        for (int qq = 0; qq < NB; ++qq) {
            double wm = (p - qq) * PI_ / PHALF, wp = (p + qq) * PI_ / PHALF;
            double Sm = (p == qq)     ? LFIT : csin_(wm * LFIT) / wm;
            double Sp = (p + qq == 0) ? LFIT : csin_(wp * LFIT) / wp;
            A[p][qq] = 0.5 * (Sm + Sp);
        }
    constexpr int NS = 128;
    double hh = LFIT / NS, gx[NS + 1] = {};
    for (int i = 0; i <= NS; ++i) gx[i] = Gfun_(i * hh);
    for (int p = 0; p < NB; ++p) {
        double s = 0;
        for (int i = 0; i <= NS; ++i) {
            double wgt = (i == 0 || i == NS) ? 1.0 : ((i & 1) ? 4.0 : 2.0);
            s += wgt * gx[i] * ccos_(p * PI_ / PHALF * (i * hh));
        }
        bv[p] = s * hh / 3.0;
    }
    for (int p = 0; p < NB; ++p) A[p][p] += 1e-8 * LFIT;
    for (int col = 0; col < NB; ++col) {
        int piv = col; double best = A[col][col] < 0 ? -A[col][col] : A[col][col];
        for (int r = col + 1; r < NB; ++r) {
            double v = A[r][col] < 0 ? -A[r][col] : A[r][col];
            if (v > best) { best = v; piv = r; }
        }
        if (piv != col) {
            for (int cc = 0; cc < NB; ++cc) { double t = A[col][cc]; A[col][cc] = A[piv][cc]; A[piv][cc] = t; }
            double t = bv[col]; bv[col] = bv[piv]; bv[piv] = t;
        }
        for (int r = col + 1; r < NB; ++r) {
            double f = A[r][col] / A[col][col];
            for (int cc = col; cc < NB; ++cc) A[r][cc] -= f * A[col][cc];
            bv[r] -= f * bv[col];
        }
    }
    double c[NB] = {};
    for (int r = NB - 1; r >= 0; --r) {
        double s = bv[r];
        for (int cc = r + 1; cc < NB; ++cc) s -= A[r][cc] * c[cc];
        c[r] = s / A[r][r];
    }
    FitT f{};
    for (int m = 0; m <= MF; ++m) {
        double rt = csqrt_(c[m] < 0 ? -c[m] : c[m]);
        f.tk[m] = (float)rt;
        f.tq[m] = (float)(c[m] < 0 ? -rt : rt);
    }
    return f;
}
constexpr FitT CF = lsFit_();

// ---------------- device ---------------------------------------------------
typedef _Float16 half8  __attribute__((ext_vector_type(8)));
typedef float    f32x16 __attribute__((ext_vector_type(16)));

__device__ __forceinline__ uint32_t pkh_(float a, float b) {
    auto v = __builtin_amdgcn_cvt_pkrtz(a, b);
    uint32_t u; __builtin_memcpy(&u, &v, 4); return u;
}

// LDS: K dbuf 2x32KB at 0; Q dbuf 2x8KB at 65536. Within a 128B row, 16B
// unit u stored at u^(row&7): even bank-group spread for both staging writes
// and frag reads (validated layout, carried from R7-R9). Epilogue sred[64][4]
// + akv[256] alias Q buf0 (only touched after the final barrier).
constexpr int KHALF = Nc * 128;           // 32768 per K buffer
constexpr int QOFF  = 2 * KHALF;          // 65536
constexpr int QHALF = 64 * 128;           // 8192 per Q buffer
constexpr int SMEM  = QOFF + 2 * QHALF;   // 81920 B -> 2 blocks/CU (163840 = LDS pool)

// 512 thr = 8 waves; 2 blocks/CU -> 4 waves/EU -> 128-reg cap (2nd arg = 4).
// Live estimate ~90 unified (r1k 16 + r1q 4 + akvr 4 + acc 32 + addr/temps)
// -> no spills. Block = 64i x 256j; wave tile 32i x 64j (acc 2x16).
__global__ __launch_bounds__(512, 4) void gatv2_mfma_kernel(
    const float* __restrict__ q, const float* __restrict__ k,
    const uint8_t* __restrict__ mask, const float* __restrict__ att,
    float* __restrict__ out)
{
    extern __shared__ char smem[];

    const int tid = threadIdx.x, lane = tid & 63, w = tid >> 6;
    const int bh = blockIdx.y, h = bh & 7, b = bh >> 3;
    const int iBlk = blockIdx.x * 64;
    const float invTwoP = (float)(1.0 / (2.0 * PHALF));

    // staging distribution: dq = 16B unit (4 d's), rw = row 0..63
    const int dq = tid & 7, rw = tid >> 3;
    const float4 a4 = *(const float4*)(att + h * Dc + 4 * dq);
    const int swS = (dq ^ (rw & 7)) << 4;              // staging unit swizzle

    // ---- K: rows rw + 64*it: load, exact Ak (shfl over dq), phase r1 ----
    const float* kbase = k + (size_t)bh * Nc * Dc;
    float r1k[16], akvr[4];
    int offK[4];
#pragma unroll
    for (int it = 0; it < 4; ++it) {
        const int j = rw + it * 64;
        const float4 kv = *(const float4*)(kbase + j * Dc + 4 * dq);
        float part = a4.x * kv.x + a4.y * kv.y + a4.z * kv.z + a4.w * kv.w;
        part += __shfl_xor(part, 1, 64);
        part += __shfl_xor(part, 2, 64);
        part += __shfl_xor(part, 4, 64);
        akvr[it] = part;                               // published in epilogue
        const float rv[4] = { kv.x, kv.y, kv.z, kv.w };
#pragma unroll
        for (int c = 0; c < 4; ++c)
            r1k[4 * it + c] = __builtin_amdgcn_fractf(rv[c] * invTwoP);
        offK[it] = j * 128 + swS;                      // (j+64)&7 == j&7
    }
    // ---- Q: row rw ----
    const float* qbase = q + ((size_t)bh * Nc + iBlk) * Dc;
    float r1q[4];
    const int offQ = rw * 128 + swS;
    {
        const float4 qv = *(const float4*)(qbase + rw * Dc + 4 * dq);
        const float rv[4] = { qv.x, qv.y, qv.z, qv.w };
#pragma unroll
        for (int c = 0; c < 4; ++c)
            r1q[c] = __builtin_amdgcn_fractf(rv[c] * invTwoP);
    }

    // ---- wave tile: wi = i-tile (32 rows), wj = j-group (64 cols) ----
    const int hi5 = lane >> 5, col = lane & 31;
    const int wi = w & 1, wj = w >> 1;
    const int baseA  = (wi * 32 + col) * 128;          // within Q buffer
    const int baseB0 = (wj * 64 + col) * 128;          // within K buffer
    const int baseB1 = baseB0 + 32 * 128;
    const int sA = col & 7;                            // row&7 same for A/B rows

    f32x16 acc[2];
#pragma unroll
    for (int jt = 0; jt < 2; ++jt)
#pragma unroll
        for (int e = 0; e < 16; ++e) acc[jt][e] = 0.0f;

    // features for chunk m recomputed from phase: r = fract(m*r1) revolutions,
    // HW v_cos/v_sin take revolutions directly. No loop-carried trig state.
    auto buildChunk = [&](int m, int kB, int qB) {
        const float tk = CF.tk[m];
        const float g0 = CF.tq[m]*a4.x, g1 = CF.tq[m]*a4.y;
        const float g2 = CF.tq[m]*a4.z, g3 = CF.tq[m]*a4.w;
        const float mf = (float)m;
#pragma unroll
        for (int it = 0; it < 4; ++it) {               // K: one b128 per row
            float cs[4], sn[4];
#pragma unroll
            for (int c = 0; c < 4; ++c) {
                const float r = __builtin_amdgcn_fractf(mf * r1k[4 * it + c]);
                cs[c] = __builtin_amdgcn_cosf(r);
                sn[c] = __builtin_amdgcn_sinf(r);
            }
            uint4 wv;
            wv.x = pkh_(tk * cs[0], tk * sn[0]);
            wv.y = pkh_(tk * cs[1], tk * sn[1]);
            wv.z = pkh_(tk * cs[2], tk * sn[2]);
            wv.w = pkh_(tk * cs[3], tk * sn[3]);
            *(uint4*)(smem + kB + offK[it]) = wv;
        }
        {                                              // Q: one b128
            float qc[4], qs[4];
#pragma unroll
            for (int c = 0; c < 4; ++c) {
                const float r = __builtin_amdgcn_fractf(mf * r1q[c]);
                qc[c] = __builtin_amdgcn_cosf(r);
                qs[c] = __builtin_amdgcn_sinf(r);
            }
            uint4 wv;
            wv.x = pkh_(g0 * qc[0], -(g0 * qs[0]));
            wv.y = pkh_(g1 * qc[1], -(g1 * qs[1]));
            wv.z = pkh_(g2 * qc[2], -(g2 * qs[2]));
            wv.w = pkh_(g3 * qc[3], -(g3 * qs[3]));
            *(uint4*)(smem + qB + offQ) = wv;
        }
    };

    auto mfmaChunk = [&](int kB, int qB) {
#pragma unroll
        for (int s = 0; s < 4; ++s) {
            const int du = ((2 * s + hi5) ^ sA) << 4;
            half8 A  = *(const half8*)(smem + qB + baseA  + du);
            half8 B0 = *(const half8*)(smem + kB + baseB0 + du);
            half8 B1 = *(const half8*)(smem + kB + baseB1 + du);
            acc[0] = __builtin_amdgcn_mfma_f32_32x32x16_f16(A, B0, acc[0], 0, 0, 0);
            acc[1] = __builtin_amdgcn_mfma_f32_32x32x16_f16(A, B1, acc[1], 0, 0, 0);
        }
    };

    // ---- pipelined chunk loop (dbuf, 1 barrier/chunk); chunk m in buf (m-1)&1
    buildChunk(1, 0, QOFF);
    __syncthreads();
#pragma unroll
    for (int m = 1; m <= MF; ++m) {
        const int p = (m - 1) & 1, pn = m & 1;
        if (m < MF) buildChunk(m + 1, pn * KHALF, QOFF + pn * QHALF);
        mfmaChunk(p * KHALF, QOFF + p * QHALF);
        __syncthreads();
    }

    // ---- epilogue: fixed-offset softmax (shift-invariant; validated R6-R9) ----
    float* sred = (float*)(smem + QOFF);          // [64][4], aliases Q buf0
    float* akv  = (float*)(smem + QOFF + 1024);   // [256],   aliases Q buf0
    if (dq == 0) {
        akv[rw      ] = akvr[0];
        akv[rw +  64] = akvr[1];
        akv[rw + 128] = akvr[2];
        akv[rw + 192] = akvr[3];
    }
    __syncthreads();

    constexpr float M0 = 24.0f;
    const int jB = wj * 64;
    const float akj0 = akv[jB + col], akj1 = akv[jB + 32 + col];
    const int iB = iBlk + wi * 32;

#pragma unroll
    for (int e = 0; e < 16; ++e) {
        const int rloc = (e & 3) + 8 * (e >> 2) + 4 * hi5;
        const int ig = iB + rloc;
        const uint8_t* mr = mask + ((size_t)(b * Nc + ig)) * Nc + jB + col;
        float v0 = fmaf(0.5f, akj0, acc[0][e]);
        float v1 = fmaf(0.5f, akj1, acc[1][e]);
        if (mr[0])  v0 = -1.0e30f;
        if (mr[32]) v1 = -1.0e30f;
        float p0 = __builtin_amdgcn_exp2f(__builtin_fminf((v0 - M0) * LOG2E, 80.0f));
        float p1 = __builtin_amdgcn_exp2f(__builtin_fminf((v1 - M0) * LOG2E, 80.0f));
        acc[0][e] = p0;
        acc[1][e] = p1;
        float sm = p0 + p1;
#pragma unroll
        for (int off = 1; off < 32; off <<= 1) sm += __shfl_xor(sm, off, 64);
        if (col == e) sred[(wi * 32 + rloc) * 4 + wj] = sm;
    }
    __syncthreads();

    float* obase = out + (size_t)bh * Nc * Nc;
#pragma unroll
    for (int e = 0; e < 16; ++e) {
        const int rloc = (e & 3) + 8 * (e >> 2) + 4 * hi5;
        const int iL = wi * 32 + rloc;
        const int ig = iB + rloc;
        const float4 tv = *(const float4*)(&sred[iL * 4]);   // broadcast read
        const float inv = __builtin_amdgcn_rcpf(tv.x + tv.y + tv.z + tv.w);
        obase[(size_t)ig * Nc + jB + col]      = acc[0][e] * inv;
        obase[(size_t)ig * Nc + jB + 32 + col] = acc[1][e] * inv;
    }
}

extern "C" void kernel_launch(void* const* d_in, const int* in_sizes, int n_in,
                              void* d_out, int out_size, void* d_ws, size_t ws_size,
                              hipStream_t stream) {
    const float*   q    = (const float*)d_in[0];
    const float*   k    = (const float*)d_in[1];
    // d_in[2] = scale (unused by the module)
    const uint8_t* mask = (const uint8_t*)d_in[3];
    const float*   att  = (const float*)d_in[4];
    float*         out  = (float*)d_out;

    (void)hipFuncSetAttribute((const void*)gatv2_mfma_kernel,
                              hipFuncAttributeMaxDynamicSharedMemorySize, SMEM);

    dim3 grid(4, Bc * Hc);        // 4 i-blocks x 128 (b,h) = 512 blocks (2/CU)
    dim3 block(512);              // 8 waves; 2 blocks/CU -> 4 waves/EU
    gatv2_mfma_kernel<<<grid, block, SMEM, stream>>>(q, k, mask, att, out);
}

// Round 2
// 97.089 us; speedup vs baseline: 1.0666x; 1.0666x over previous
//
#include <hip/hip_runtime.h>
#include <stdint.h>
#include <stddef.h>

// Problem constants: B=16, H=8, N=256, D=32
constexpr int Bc = 16, Hc = 8, Nc = 256, Dc = 32;
constexpr float LOG2E = 1.44269504088896340736f;

// score_ij = sum_d a_d * silu(q_id + k_jd); silu(x) = x/2 + G(x),
// G(x)=(x/2)tanh(x/2) even. Fit G ~ sum_m c_m cos(m*pi*x/PHALF) (constexpr LS);
// cos(w(q+k)) separates -> f16 MFMA contraction. j-constant terms cancel in
// softmax; 0.5*Ak_j survives (exact fp32).
//
// R11 post-mortem: R10's trans-recompute ADDED ~6us of 1/4-rate trans issue
// (VALUBusy 2.4->33.5); warm kernel 43 -> 48.5us. Spill theory was wrong
// (VGPR 60 << 128 cap). Revert to chained rotation (4 full-rate VALU/elem) at
// 1024 thr where its 48-reg state fits. The real stall attacked here:
// (a) per chunk, 5 ds_writes issued BEFORE 12 ds_reads put the write drain on
//     the MFMA lgkmcnt chain (in-order counter) -> reorder: reads first,
//     rotation VALU covers read latency, writes after the first 6 reads;
// (b) epilogue row-sum used 80 shfl (LDS pipe); multi-value butterfly = 16;
// (c) setprio(1) around MFMA cluster; drop dead last-chunk barrier.
constexpr int    MF    = 10;
constexpr double PHALF = 9.7;
constexpr double LFIT  = 9.0;

// ---------------- constexpr math (no hand-typed magic numbers) -------------
constexpr double PI_ = 3.14159265358979323846;

constexpr double cexp_(double x) {
    int n = (int)(x >= 0 ? x + 0.5 : x - 0.5);
    double f = x - n, t = 1.0, s = 1.0;
    for (int i = 1; i <= 26; ++i) { t *= f / i; s += t; }
    const double E = 2.71828182845904523536;
    double en = 1.0, bb = n >= 0 ? E : 1.0 / E;
    int an = n < 0 ? -n : n;
    for (int i = 0; i < an; ++i) en *= bb;
    return s * en;
}
constexpr double creduce_(double x) {
    while (x >  PI_) x -= 2.0 * PI_;
    while (x < -PI_) x += 2.0 * PI_;
    return x;
}
constexpr double ccos_(double x0) {
    double x = creduce_(x0), x2 = x * x, t = 1.0, s = 1.0;
    for (int i = 1; i <= 16; ++i) { t *= -x2 / ((2.0*i - 1.0) * (2.0*i)); s += t; }
    return s;
}
constexpr double csin_(double x0) {
    double x = creduce_(x0), x2 = x * x, t = x, s = x;
    for (int i = 1; i <= 16; ++i) { t *= -x2 / ((2.0*i) * (2.0*i + 1.0)); s += t; }
    return s;
}
constexpr double Gfun_(double x) {
    double z = x < 0 ? -x : x;
    double e = cexp_(z);
    return 0.5 * z * ((e - 1.0) / (e + 1.0));
}
constexpr double csqrt_(double x) {
    if (x <= 0) return 0;
    double r = x > 1 ? x : 1;
    for (int i = 0; i < 40; ++i) r = 0.5 * (r + x / r);
    return r;
}

struct FitT { float tk[MF + 1]; float tq[MF + 1]; };

constexpr FitT lsFit_() {
    constexpr int NB = MF + 1;
    double A[NB][NB] = {}, bv[NB] = {};
    for (int p = 0; p < NB; ++p)
        for (int qq = 0; qq < NB; ++qq) {
            double wm = (p - qq) * PI_ / PHALF, wp = (p + qq) * PI_ / PHALF;
            double Sm = (p == qq)     ? LFIT : csin_(wm * LFIT) / wm;
            double Sp = (p + qq == 0) ? LFIT : csin_(wp * LFIT) / wp;
            A[p][qq] = 0.5 * (Sm + Sp);
        }
    constexpr int NS = 128;
    double hh = LFIT / NS, gx[NS + 1] = {};
    for (int i = 0; i <= NS; ++i) gx[i] = Gfun_(i * hh);
    for (int p = 0; p < NB; ++p) {
        double s = 0;
        for (int i = 0; i <= NS; ++i) {
            double wgt = (i == 0 || i == NS) ? 1.0 : ((i & 1) ? 4.0 : 2.0);
            s += wgt * gx[i] * ccos_(p * PI_ / PHALF * (i * hh));
        }
        bv[p] = s * hh / 3.0;
    }
    for (int p = 0; p < NB; ++p) A[p][p] += 1e-8 * LFIT;
    for (int col = 0; col < NB; ++col) {
        int piv = col; double best = A[col][col] < 0 ? -A[col][col] : A[col][col];
        for (int r = col + 1; r < NB; ++r) {
            double v = A[r][col] < 0 ? -A[r][col] : A[r][col];
            if (v > best) { best = v; piv = r; }
        }
        if (piv != col) {
            for (int cc = 0; cc < NB; ++cc) { double t = A[col][cc]; A[col][cc] = A[piv][cc]; A[piv][cc] = t; }
            double t = bv[col]; bv[col] = bv[piv]; bv[piv] = t;
        }
        for (int r = col + 1; r < NB; ++r) {
            double f = A[r][col] / A[col][col];
            for (int cc = col; cc < NB; ++cc) A[r][cc] -= f * A[col][cc];
            bv[r] -= f * bv[col];
        }
    }
    double c[NB] = {};
    for (int r = NB - 1; r >= 0; --r) {
        double s = bv[r];
        for (int cc = r + 1; cc < NB; ++cc) s -= A[r][cc] * c[cc];
        c[r] = s / A[r][r];
    }
    FitT f{};
    for (int m = 0; m <= MF; ++m) {
        double rt = csqrt_(c[m] < 0 ? -c[m] : c[m]);
        f.tk[m] = (float)rt;
        f.tq[m] = (float)(c[m] < 0 ? -rt : rt);
    }
    return f;
}
constexpr FitT CF = lsFit_();

// ---------------- device ---------------------------------------------------
typedef _Float16 half8  __attribute__((ext_vector_type(8)));
typedef float    f32x16 __attribute__((ext_vector_type(16)));

__device__ __forceinline__ uint32_t pkh_(float a, float b) {
    auto v = __builtin_amdgcn_cvt_pkrtz(a, b);
    uint32_t u; __builtin_memcpy(&u, &v, 4); return u;
}

// LDS layout per buffer: K features 256 rows x 128 B (32 KB), then Q features
// 128 rows x 128 B (16 KB). Within a row, 16B unit u stored at u^(row&7):
// balanced bank groups for both b128 staging writes and b128 frag reads.
constexpr int KB_  = Nc * 128;            // 32768
constexpr int QB_  = 128 * 128;           // 16384
constexpr int BUF  = KB_ + QB_;           // 49152
constexpr int SRED_OFF = 2 * BUF;         // 98304, sred[128][4] f32
constexpr int AKV_OFF  = SRED_OFF + 2048; // akv[256] f32
constexpr int SMEM     = AKV_OFF + 1024;  // 101376 B

// 1024 thr = 16 waves = 4 waves/EU -> 128-reg cap. Live estimate ~126
// (rotation state 48 + acc 32 + 6 frag half8 24 + misc ~22) -> no spill.
// Block = 128i x 256j; wave tile 32i x 64j (acc 2x16); dbuf, 1 barrier/chunk.
__global__ __launch_bounds__(1024, 4) void gatv2_mfma_kernel(
    const float* __restrict__ q, const float* __restrict__ k,
    const uint8_t* __restrict__ mask, const float* __restrict__ att,
    float* __restrict__ out)
{
    extern __shared__ char smem[];
    float* sred = (float*)(smem + SRED_OFF);
    float* akv  = (float*)(smem + AKV_OFF);

    const int tid = threadIdx.x, lane = tid & 63, w = tid >> 6;
    const int bh = blockIdx.y, h = bh & 7, b = bh >> 3;
    const int iBlk = blockIdx.x * 128;
    const float invTwoP = (float)(1.0 / (2.0 * PHALF));

    // staging distribution: dq = 16B unit (4 d's), rw = row 0..127
    const int dq = tid & 7, rw = tid >> 3;
    const float4 a4 = *(const float4*)(att + h * Dc + 4 * dq);
    const int swS = (dq ^ (rw & 7)) << 4;              // staging unit swizzle

    // ---- K: rows {rw, rw+128}: load, exact Ak (shfl over dq), rot state ----
    const float* kbase = k + (size_t)bh * Nc * Dc;
    float kc1[8], ks1[8], kcm[8], ksm[8];
    int offK[2];
#pragma unroll
    for (int it = 0; it < 2; ++it) {
        const int j = rw + it * 128;
        const float4 kv = *(const float4*)(kbase + j * Dc + 4 * dq);
        float part = a4.x * kv.x + a4.y * kv.y + a4.z * kv.z + a4.w * kv.w;
        part += __shfl_xor(part, 1, 64);
        part += __shfl_xor(part, 2, 64);
        part += __shfl_xor(part, 4, 64);
        if (dq == 0) akv[j] = part;
        const float rv[4] = { kv.x, kv.y, kv.z, kv.w };
#pragma unroll
        for (int c = 0; c < 4; ++c) {
            float r = __builtin_amdgcn_fractf(rv[c] * invTwoP);
            kc1[4*it+c] = __builtin_amdgcn_cosf(r);
            ks1[4*it+c] = __builtin_amdgcn_sinf(r);
            kcm[4*it+c] = kc1[4*it+c];
            ksm[4*it+c] = ks1[4*it+c];
        }
        offK[it] = j * 128 + swS;                      // (j+128)&7 == j&7
    }
    // ---- Q: row rw ----
    const float* qbase = q + ((size_t)bh * Nc + iBlk) * Dc;
    float qc1[4], qs1[4], qcm[4], qsm[4];
    const int offQ = KB_ + rw * 128 + swS;
    {
        const float4 qv = *(const float4*)(qbase + rw * Dc + 4 * dq);
        const float rv[4] = { qv.x, qv.y, qv.z, qv.w };
#pragma unroll
        for (int c = 0; c < 4; ++c) {
            float r = __builtin_amdgcn_fractf(rv[c] * invTwoP);
            qc1[c] = __builtin_amdgcn_cosf(r);
            qs1[c] = __builtin_amdgcn_sinf(r);
            qcm[c] = qc1[c]; qsm[c] = qs1[c];
        }
    }

    // ---- wave tile: wi = i-tile (32 rows), wj = j-group (64 cols) ----
    const int hi5 = lane >> 5, col = lane & 31;
    const int wi = w & 3, wj = w >> 2;
    const int baseA  = KB_ + (wi * 32 + col) * 128;
    const int baseB0 = (wj * 64 + col) * 128, baseB1 = baseB0 + 32 * 128;
    const int sA = col & 7;                            // row&7 same for A/B rows

    f32x16 acc[2];
#pragma unroll
    for (int jt = 0; jt < 2; ++jt)
#pragma unroll
        for (int e = 0; e < 16; ++e) acc[jt][e] = 0.0f;

    // build chunk mN (state must hold angle mN); writes 3 b128 to dstOff
    auto buildWrite = [&](int mN, int dstOff) {
        const float tk = CF.tk[mN];
        const float g0 = CF.tq[mN]*a4.x, g1 = CF.tq[mN]*a4.y;
        const float g2 = CF.tq[mN]*a4.z, g3 = CF.tq[mN]*a4.w;
#pragma unroll
        for (int it = 0; it < 2; ++it) {               // K: one b128 per row
            uint4 wv;
            wv.x = pkh_(tk * kcm[4*it+0], tk * ksm[4*it+0]);
            wv.y = pkh_(tk * kcm[4*it+1], tk * ksm[4*it+1]);
            wv.z = pkh_(tk * kcm[4*it+2], tk * ksm[4*it+2]);
            wv.w = pkh_(tk * kcm[4*it+3], tk * ksm[4*it+3]);
            *(uint4*)(smem + dstOff + offK[it]) = wv;
        }
        {                                              // Q: one b128
            uint4 wv;
            wv.x = pkh_(g0 * qcm[0], -(g0 * qsm[0]));
            wv.y = pkh_(g1 * qcm[1], -(g1 * qsm[1]));
            wv.z = pkh_(g2 * qcm[2], -(g2 * qsm[2]));
            wv.w = pkh_(g3 * qcm[3], -(g3 * qsm[3]));
            *(uint4*)(smem + dstOff + offQ) = wv;
        }
    };
    auto rotate = [&]() {                              // state m -> m+1
#pragma unroll
        for (int e = 0; e < 8; ++e) {
            float cn = fmaf(kc1[e], kcm[e], -(ks1[e] * ksm[e]));
            float sn = fmaf(ks1[e], kcm[e],   kc1[e] * ksm[e]);
            kcm[e] = cn; ksm[e] = sn;
        }
#pragma unroll
        for (int e = 0; e < 4; ++e) {
            float cn = fmaf(qc1[e], qcm[e], -(qs1[e] * qsm[e]));
            float sn = fmaf(qs1[e], qcm[e],   qc1[e] * qsm[e]);
            qcm[e] = cn; qsm[e] = sn;
        }
    };
    auto loadFrags = [&](int srcOff, int s, half8& A, half8& B0, half8& B1) {
        const int du = ((2 * s + hi5) ^ sA) << 4;
        A  = *(const half8*)(smem + srcOff + baseA  + du);
        B0 = *(const half8*)(smem + srcOff + baseB0 + du);
        B1 = *(const half8*)(smem + srcOff + baseB1 + du);
    };

    // ---- pipelined chunk loop: reads FIRST (lgkmcnt is in-order; writes
    // issued after the s0/s1 reads so MFMA waits never include write drain),
    // rotation VALU covers read latency, s2/s3 reads pipelined into MFMAs.
    buildWrite(1, 0);
    rotate();
    __syncthreads();
#pragma unroll
    for (int m = 1; m <= MF; ++m) {
        const int srcOff = ((m - 1) & 1) * BUF;
        const int dstOff = (m & 1) * BUF;
        half8 A0, B00, B10, A1, B01, B11;
        loadFrags(srcOff, 0, A0, B00, B10);
        loadFrags(srcOff, 1, A1, B01, B11);
        if (m < MF) { buildWrite(m + 1, dstOff); rotate(); }
        __builtin_amdgcn_s_setprio(1);
        acc[0] = __builtin_amdgcn_mfma_f32_32x32x16_f16(A0, B00, acc[0], 0, 0, 0);
        acc[1] = __builtin_amdgcn_mfma_f32_32x32x16_f16(A0, B10, acc[1], 0, 0, 0);
        loadFrags(srcOff, 2, A0, B00, B10);
        acc[0] = __builtin_amdgcn_mfma_f32_32x32x16_f16(A1, B01, acc[0], 0, 0, 0);
        acc[1] = __builtin_amdgcn_mfma_f32_32x32x16_f16(A1, B11, acc[1], 0, 0, 0);
        loadFrags(srcOff, 3, A1, B01, B11);
        acc[0] = __builtin_amdgcn_mfma_f32_32x32x16_f16(A0, B00, acc[0], 0, 0, 0);
        acc[1] = __builtin_amdgcn_mfma_f32_32x32x16_f16(A0, B10, acc[1], 0, 0, 0);
        acc[0] = __builtin_amdgcn_mfma_f32_32x32x16_f16(A1, B01, acc[0], 0, 0, 0);
        acc[1] = __builtin_amdgcn_mfma_f32_32x32x16_f16(A1, B11, acc[1], 0, 0, 0);
        __builtin_amdgcn_s_setprio(0);
        if (m < MF) __syncthreads();                   // last barrier is dead
    }

    // ---- epilogue: fixed-offset softmax (shift-invariant; validated R6-R9) ----
    constexpr float M0 = 24.0f;
    const int jB = wj * 64;
    const float akj0 = akv[jB + col], akj1 = akv[jB + 32 + col];
    const int iB = iBlk + wi * 32;

    float v[16];
#pragma unroll
    for (int e = 0; e < 16; ++e) {
        const int rloc = (e & 3) + 8 * (e >> 2) + 4 * hi5;
        const int ig = iB + rloc;
        const uint8_t* mr = mask + ((size_t)(b * Nc + ig)) * Nc + jB + col;
        float v0 = fmaf(0.5f, akj0, acc[0][e]);
        float v1 = fmaf(0.5f, akj1, acc[1][e]);
        if (mr[0])  v0 = -1.0e30f;
        if (mr[32]) v1 = -1.0e30f;
        float p0 = __builtin_amdgcn_exp2f(__builtin_fminf((v0 - M0) * LOG2E, 80.0f));
        float p1 = __builtin_amdgcn_exp2f(__builtin_fminf((v1 - M0) * LOG2E, 80.0f));
        acc[0][e] = p0;
        acc[1][e] = p1;
        v[e] = p0 + p1;
    }
    // multi-value butterfly: fold 16 row-values over xor {16,8,4,2}, finish
    // with xor 1. After fold, lane col holds the 32-col sum for row
    // e = 8*bit4 + 4*bit3 + 2*bit2 + bit1 (lanes col, col^1 duplicate).
    float u8[8];
#pragma unroll
    for (int j = 0; j < 8; ++j) {
        float mine = (col & 16) ? v[j + 8] : v[j];
        float send = (col & 16) ? v[j]     : v[j + 8];
        u8[j] = mine + __shfl_xor(send, 16, 64);
    }
    float u4[4];
#pragma unroll
    for (int j = 0; j < 4; ++j) {
        float mine = (col & 8) ? u8[j + 4] : u8[j];
        float send = (col & 8) ? u8[j]     : u8[j + 4];
        u4[j] = mine + __shfl_xor(send, 8, 64);
    }
    float u2[2];
#pragma unroll
    for (int j = 0; j < 2; ++j) {
        float mine = (col & 4) ? u4[j + 2] : u4[j];
        float send = (col & 4) ? u4[j]     : u4[j + 2];
        u2[j] = mine + __shfl_xor(send, 4, 64);
    }
    float t1;
    {
        float mine = (col & 2) ? u2[1] : u2[0];
        float send = (col & 2) ? u2[0] : u2[1];
        t1 = mine + __shfl_xor(send, 2, 64);
    }
    t1 += __shfl_xor(t1, 1, 64);
    {
        const int eL = ((col & 16) ? 8 : 0) + ((col & 8) ? 4 : 0)
                     + ((col & 4) ? 2 : 0) + ((col & 2) ? 1 : 0);
        const int rl = (eL & 3) + 8 * (eL >> 2) + 4 * hi5;
        if (!(col & 1)) sred[(wi * 32 + rl) * 4 + wj] = t1;
    }
    __syncthreads();

    float* obase = out + (size_t)bh * Nc * Nc;
#pragma unroll
    for (int e = 0; e < 16; ++e) {
        const int rloc = (e & 3) + 8 * (e >> 2) + 4 * hi5;
        const int iL = wi * 32 + rloc;
        const int ig = iB + rloc;
        const float4 tv = *(const float4*)(&sred[iL * 4]);   // broadcast read
        const float inv = __builtin_amdgcn_rcpf(tv.x + tv.y + tv.z + tv.w);
        obase[(size_t)ig * Nc + jB + col]      = acc[0][e] * inv;
        obase[(size_t)ig * Nc + jB + 32 + col] = acc[1][e] * inv;
    }
}

extern "C" void kernel_launch(void* const* d_in, const int* in_sizes, int n_in,
                              void* d_out, int out_size, void* d_ws, size_t ws_size,
                              hipStream_t stream) {
    const float*   q    = (const float*)d_in[0];
    const float*   k    = (const float*)d_in[1];
    // d_in[2] = scale (unused by the module)
    const uint8_t* mask = (const uint8_t*)d_in[3];
    const float*   att  = (const float*)d_in[4];
    float*         out  = (float*)d_out;

    (void)hipFuncSetAttribute((const void*)gatv2_mfma_kernel,
                              hipFuncAttributeMaxDynamicSharedMemorySize, SMEM);

    dim3 grid(2, Bc * Hc);        // 2 i-blocks x 128 (b,h) = 256 blocks (1/CU)
    dim3 block(1024);             // 16 waves = 4 waves/EU
    gatv2_mfma_kernel<<<grid, block, SMEM, stream>>>(q, k, mask, att, out);
}

// Round 3
// 92.224 us; speedup vs baseline: 1.1229x; 1.0528x over previous
//
#include <hip/hip_runtime.h>
#include <stdint.h>
#include <stddef.h>

// Problem constants: B=16, H=8, N=256, D=32
constexpr int Bc = 16, Hc = 8, Nc = 256, Dc = 32;
constexpr float LOG2E = 1.44269504088896340736f;

// score_ij = sum_d a_d * silu(q_id + k_jd); silu(x) = x/2 + G(x),
// G(x)=(x/2)tanh(x/2) even. Fit G ~ sum_m c_m cos(m*pi*x/PHALF) (constexpr LS);
// cos(w(q+k)) separates -> f16 MFMA contraction. j-constant terms cancel in
// softmax; 0.5*Ak_j survives (exact fp32).
//
// R12: cross-round A/B evidence: kernel time tracks LDS b128 wave-ops/chunk
// almost exactly (r1: 272 ops -> 48.5us; r0/r2: 240 ops -> 43us; ratio 1.13
// both). => LDS-pipe-bound at ~33 cyc/op under contention. Lever = fewer ops:
// 64x64 wave tiles (1.0 read/MFMA vs 1.5) at 8 waves/512thr -> 176 ops/chunk
// (-27%). acc 4x16 (AGPR), state 96 VGPR -> launch_bounds(512,2), no spill.
// Keep reads-first order, setprio MFMA cluster, butterfly epilogue (x2 i-sub).
constexpr int    MF    = 10;
constexpr double PHALF = 9.7;
constexpr double LFIT  = 9.0;

// ---------------- constexpr math (no hand-typed magic numbers) -------------
constexpr double PI_ = 3.14159265358979323846;

constexpr double cexp_(double x) {
    int n = (int)(x >= 0 ? x + 0.5 : x - 0.5);
    double f = x - n, t = 1.0, s = 1.0;
    for (int i = 1; i <= 26; ++i) { t *= f / i; s += t; }
    const double E = 2.71828182845904523536;
    double en = 1.0, bb = n >= 0 ? E : 1.0 / E;
    int an = n < 0 ? -n : n;
    for (int i = 0; i < an; ++i) en *= bb;
    return s * en;
}
constexpr double creduce_(double x) {
    while (x >  PI_) x -= 2.0 * PI_;
    while (x < -PI_) x += 2.0 * PI_;
    return x;
}
constexpr double ccos_(double x0) {
    double x = creduce_(x0), x2 = x * x, t = 1.0, s = 1.0;
    for (int i = 1; i <= 16; ++i) { t *= -x2 / ((2.0*i - 1.0) * (2.0*i)); s += t; }
    return s;
}
constexpr double csin_(double x0) {
    double x = creduce_(x0), x2 = x * x, t = x, s = x;
    for (int i = 1; i <= 16; ++i) { t *= -x2 / ((2.0*i) * (2.0*i + 1.0)); s += t; }
    return s;
}
constexpr double Gfun_(double x) {
    double z = x < 0 ? -x : x;
    double e = cexp_(z);
    return 0.5 * z * ((e - 1.0) / (e + 1.0));
}
constexpr double csqrt_(double x) {
    if (x <= 0) return 0;
    double r = x > 1 ? x : 1;
    for (int i = 0; i < 40; ++i) r = 0.5 * (r + x / r);
    return r;
}

struct FitT { float tk[MF + 1]; float tq[MF + 1]; };

constexpr FitT lsFit_() {
    constexpr int NB = MF + 1;
    double A[NB][NB] = {}, bv[NB] = {};
    for (int p = 0; p < NB; ++p)
        for (int qq = 0; qq < NB; ++qq) {
            double wm = (p - qq) * PI_ / PHALF, wp = (p + qq) * PI_ / PHALF;
            double Sm = (p == qq)     ? LFIT : csin_(wm * LFIT) / wm;
            double Sp = (p + qq == 0) ? LFIT : csin_(wp * LFIT) / wp;
            A[p][qq] = 0.5 * (Sm + Sp);
        }
    constexpr int NS = 128;
    double hh = LFIT / NS, gx[NS + 1] = {};
    for (int i = 0; i <= NS; ++i) gx[i] = Gfun_(i * hh);
    for (int p = 0; p < NB; ++p) {
        double s = 0;
        for (int i = 0; i <= NS; ++i) {
            double wgt = (i == 0 || i == NS) ? 1.0 : ((i & 1) ? 4.0 : 2.0);
            s += wgt * gx[i] * ccos_(p * PI_ / PHALF * (i * hh));
        }
        bv[p] = s * hh / 3.0;
    }
    for (int p = 0; p < NB; ++p) A[p][p] += 1e-8 * LFIT;
    for (int col = 0; col < NB; ++col) {
        int piv = col; double best = A[col][col] < 0 ? -A[col][col] : A[col][col];
        for (int r = col + 1; r < NB; ++r) {
            double v = A[r][col] < 0 ? -A[r][col] : A[r][col];
            if (v > best) { best = v; piv = r; }
        }
        if (piv != col) {
            for (int cc = 0; cc < NB; ++cc) { double t = A[col][cc]; A[col][cc] = A[piv][cc]; A[piv][cc] = t; }
            double t = bv[col]; bv[col] = bv[piv]; bv[piv] = t;
        }
        for (int r = col + 1; r < NB; ++r) {
            double f = A[r][col] / A[col][col];
            for (int cc = col; cc < NB; ++cc) A[r][cc] -= f * A[col][cc];
            bv[r] -= f * bv[col];
        }
    }
    double c[NB] = {};
    for (int r = NB - 1; r >= 0; --r) {
        double s = bv[r];
        for (int cc = r + 1; cc < NB; ++cc) s -= A[r][cc] * c[cc];
        c[r] = s / A[r][r];
    }
    FitT f{};
    for (int m = 0; m <= MF; ++m) {
        double rt = csqrt_(c[m] < 0 ? -c[m] : c[m]);
        f.tk[m] = (float)rt;
        f.tq[m] = (float)(c[m] < 0 ? -rt : rt);
    }
    return f;
}
constexpr FitT CF = lsFit_();

// ---------------- device ---------------------------------------------------
typedef _Float16 half8  __attribute__((ext_vector_type(8)));
typedef float    f32x16 __attribute__((ext_vector_type(16)));

__device__ __forceinline__ uint32_t pkh_(float a, float b) {
    auto v = __builtin_amdgcn_cvt_pkrtz(a, b);
    uint32_t u; __builtin_memcpy(&u, &v, 4); return u;
}

// LDS layout per buffer: K features 256 rows x 128 B (32 KB), then Q features
// 128 rows x 128 B (16 KB). Within a row, 16B unit u stored at u^(row&7):
// balanced bank groups for both b128 staging writes and b128 frag reads.
constexpr int KB_  = Nc * 128;            // 32768
constexpr int QB_  = 128 * 128;           // 16384
constexpr int BUF  = KB_ + QB_;           // 49152
constexpr int SRED_OFF = 2 * BUF;         // 98304, sred[128][4] f32
constexpr int AKV_OFF  = SRED_OFF + 2048; // akv[256] f32
constexpr int SMEM     = AKV_OFF + 1024;  // 101376 B

// 512 thr = 8 waves, 1 block/CU (101 KB LDS) -> 2 waves/EU -> 256-reg cap.
// Live estimate ~224 unified (state 96 + frags 32 + acc 64 AGPR + misc ~32).
// Block = 128i x 256j; wave tile 64i x 64j (acc 2x2x16); dbuf, 1 barrier/chunk.
__global__ __launch_bounds__(512, 2) void gatv2_mfma_kernel(
    const float* __restrict__ q, const float* __restrict__ k,
    const uint8_t* __restrict__ mask, const float* __restrict__ att,
    float* __restrict__ out)
{
    extern __shared__ char smem[];
    float* sred = (float*)(smem + SRED_OFF);
    float* akv  = (float*)(smem + AKV_OFF);

    const int tid = threadIdx.x, lane = tid & 63, w = tid >> 6;
    const int bh = blockIdx.y, h = bh & 7, b = bh >> 3;
    const int iBlk = blockIdx.x * 128;
    const float invTwoP = (float)(1.0 / (2.0 * PHALF));

    // staging distribution: dq = 16B unit (4 d's), rw = row 0..63
    const int dq = tid & 7, rw = tid >> 3;
    const float4 a4 = *(const float4*)(att + h * Dc + 4 * dq);
    const int swS = (dq ^ (rw & 7)) << 4;              // staging unit swizzle

    // ---- K: rows rw+64*it (it=0..3): load, exact Ak (shfl), rot state ----
    const float* kbase = k + (size_t)bh * Nc * Dc;
    float kc1[16], ks1[16], kcm[16], ksm[16];
    int offK[4];
#pragma unroll
    for (int it = 0; it < 4; ++it) {
        const int j = rw + it * 64;
        const float4 kv = *(const float4*)(kbase + j * Dc + 4 * dq);
        float part = a4.x * kv.x + a4.y * kv.y + a4.z * kv.z + a4.w * kv.w;
        part += __shfl_xor(part, 1, 64);
        part += __shfl_xor(part, 2, 64);
        part += __shfl_xor(part, 4, 64);
        if (dq == 0) akv[j] = part;
        const float rv[4] = { kv.x, kv.y, kv.z, kv.w };
#pragma unroll
        for (int c = 0; c < 4; ++c) {
            float r = __builtin_amdgcn_fractf(rv[c] * invTwoP);
            kc1[4*it+c] = __builtin_amdgcn_cosf(r);
            ks1[4*it+c] = __builtin_amdgcn_sinf(r);
            kcm[4*it+c] = kc1[4*it+c];
            ksm[4*it+c] = ks1[4*it+c];
        }
        offK[it] = j * 128 + swS;                      // (j+64)&7 == j&7
    }
    // ---- Q: rows rw+64*it (it=0..1) ----
    const float* qbase = q + ((size_t)bh * Nc + iBlk) * Dc;
    float qc1[8], qs1[8], qcm[8], qsm[8];
    int offQ[2];
#pragma unroll
    for (int it = 0; it < 2; ++it) {
        const int iq = rw + it * 64;
        const float4 qv = *(const float4*)(qbase + iq * Dc + 4 * dq);
        const float rv[4] = { qv.x, qv.y, qv.z, qv.w };
#pragma unroll
        for (int c = 0; c < 4; ++c) {
            float r = __builtin_amdgcn_fractf(rv[c] * invTwoP);
            qc1[4*it+c] = __builtin_amdgcn_cosf(r);
            qs1[4*it+c] = __builtin_amdgcn_sinf(r);
            qcm[4*it+c] = qc1[4*it+c];
            qsm[4*it+c] = qs1[4*it+c];
        }
        offQ[it] = KB_ + iq * 128 + swS;
    }

    // ---- wave tile: wi = i-tile (64 rows), wj = j-group (64 cols) ----
    const int hi5 = lane >> 5, col = lane & 31;
    const int wi = w & 1, wj = w >> 1;
    const int baseA0 = KB_ + (wi * 64 + col) * 128, baseA1 = baseA0 + 32 * 128;
    const int baseB0 = (wj * 64 + col) * 128,       baseB1 = baseB0 + 32 * 128;
    const int sA = col & 7;                            // row&7 same for all rows

    f32x16 acc[2][2];
#pragma unroll
    for (int i2 = 0; i2 < 2; ++i2)
#pragma unroll
        for (int j2 = 0; j2 < 2; ++j2)
#pragma unroll
            for (int e = 0; e < 16; ++e) acc[i2][j2][e] = 0.0f;

    // build chunk mN (state must hold angle mN); writes 6 b128 to dstOff
    auto buildWrite = [&](int mN, int dstOff) {
        const float tk = CF.tk[mN];
        const float g0 = CF.tq[mN]*a4.x, g1 = CF.tq[mN]*a4.y;
        const float g2 = CF.tq[mN]*a4.z, g3 = CF.tq[mN]*a4.w;
#pragma unroll
        for (int it = 0; it < 4; ++it) {               // K: one b128 per row
            uint4 wv;
            wv.x = pkh_(tk * kcm[4*it+0], tk * ksm[4*it+0]);
            wv.y = pkh_(tk * kcm[4*it+1], tk * ksm[4*it+1]);
            wv.z = pkh_(tk * kcm[4*it+2], tk * ksm[4*it+2]);
            wv.w = pkh_(tk * kcm[4*it+3], tk * ksm[4*it+3]);
            *(uint4*)(smem + dstOff + offK[it]) = wv;
        }
#pragma unroll
        for (int it = 0; it < 2; ++it) {               // Q: one b128 per row
            uint4 wv;
            wv.x = pkh_(g0 * qcm[4*it+0], -(g0 * qsm[4*it+0]));
            wv.y = pkh_(g1 * qcm[4*it+1], -(g1 * qsm[4*it+1]));
            wv.z = pkh_(g2 * qcm[4*it+2], -(g2 * qsm[4*it+2]));
            wv.w = pkh_(g3 * qcm[4*it+3], -(g3 * qsm[4*it+3]));
            *(uint4*)(smem + dstOff + offQ[it]) = wv;
        }
    };
    auto rotate = [&]() {                              // state m -> m+1
#pragma unroll
        for (int e = 0; e < 16; ++e) {
            float cn = fmaf(kc1[e], kcm[e], -(ks1[e] * ksm[e]));
            float sn = fmaf(ks1[e], kcm[e],   kc1[e] * ksm[e]);
            kcm[e] = cn; ksm[e] = sn;
        }
#pragma unroll
        for (int e = 0; e < 8; ++e) {
            float cn = fmaf(qc1[e], qcm[e], -(qs1[e] * qsm[e]));
            float sn = fmaf(qs1[e], qcm[e],   qc1[e] * qsm[e]);
            qcm[e] = cn; qsm[e] = sn;
        }
    };
    auto loadFrags = [&](int srcOff, int s, half8& A0, half8& A1,
                         half8& B0, half8& B1) {
        const int du = ((2 * s + hi5) ^ sA) << 4;
        A0 = *(const half8*)(smem + srcOff + baseA0 + du);
        A1 = *(const half8*)(smem + srcOff + baseA1 + du);
        B0 = *(const half8*)(smem + srcOff + baseB0 + du);
        B1 = *(const half8*)(smem + srcOff + baseB1 + du);
    };
    auto mfma4 = [&](half8 A0, half8 A1, half8 B0, half8 B1) {
        acc[0][0] = __builtin_amdgcn_mfma_f32_32x32x16_f16(A0, B0, acc[0][0], 0, 0, 0);
        acc[0][1] = __builtin_amdgcn_mfma_f32_32x32x16_f16(A0, B1, acc[0][1], 0, 0, 0);
        acc[1][0] = __builtin_amdgcn_mfma_f32_32x32x16_f16(A1, B0, acc[1][0], 0, 0, 0);
        acc[1][1] = __builtin_amdgcn_mfma_f32_32x32x16_f16(A1, B1, acc[1][1], 0, 0, 0);
    };

    // ---- pipelined chunk loop: reads first (writes never on MFMA lgkm path),
    // rotation VALU covers read latency, s2/s3 reads pipelined into MFMAs.
    buildWrite(1, 0);
    rotate();
    __syncthreads();
#pragma unroll
    for (int m = 1; m <= MF; ++m) {
        const int srcOff = ((m - 1) & 1) * BUF;
        const int dstOff = (m & 1) * BUF;
        half8 A0a, A1a, B0a, B1a, A0b, A1b, B0b, B1b;
        loadFrags(srcOff, 0, A0a, A1a, B0a, B1a);
        loadFrags(srcOff, 1, A0b, A1b, B0b, B1b);
        if (m < MF) { buildWrite(m + 1, dstOff); rotate(); }
        __builtin_amdgcn_s_setprio(1);
        mfma4(A0a, A1a, B0a, B1a);
        loadFrags(srcOff, 2, A0a, A1a, B0a, B1a);
        mfma4(A0b, A1b, B0b, B1b);
        loadFrags(srcOff, 3, A0b, A1b, B0b, B1b);
        mfma4(A0a, A1a, B0a, B1a);
        mfma4(A0b, A1b, B0b, B1b);
        __builtin_amdgcn_s_setprio(0);
        if (m < MF) __syncthreads();                   // last barrier is dead
    }

    // ---- epilogue: fixed-offset softmax (shift-invariant; validated R6-R9) ----
    constexpr float M0 = 24.0f;
    const int jB = wj * 64;
    const float akj0 = akv[jB + col], akj1 = akv[jB + 32 + col];
    const int iB = iBlk + wi * 64;

#pragma unroll
    for (int i2 = 0; i2 < 2; ++i2) {
        float v[16];
#pragma unroll
        for (int e = 0; e < 16; ++e) {
            const int rloc = (e & 3) + 8 * (e >> 2) + 4 * hi5;
            const int ig = iB + i2 * 32 + rloc;
            const uint8_t* mr = mask + ((size_t)(b * Nc + ig)) * Nc + jB + col;
            float v0 = fmaf(0.5f, akj0, acc[i2][0][e]);
            float v1 = fmaf(0.5f, akj1, acc[i2][1][e]);
            if (mr[0])  v0 = -1.0e30f;
            if (mr[32]) v1 = -1.0e30f;
            float p0 = __builtin_amdgcn_exp2f(__builtin_fminf((v0 - M0) * LOG2E, 80.0f));
            float p1 = __builtin_amdgcn_exp2f(__builtin_fminf((v1 - M0) * LOG2E, 80.0f));
            acc[i2][0][e] = p0;
            acc[i2][1][e] = p1;
            v[e] = p0 + p1;
        }
        // multi-value butterfly: fold 16 row-values over xor {16,8,4,2}, then
        // xor 1. Lane col ends holding the 32-col sum for row
        // eL = 8*bit4 + 4*bit3 + 2*bit2 + bit1 (lanes col, col^1 duplicate).
        float u8[8];
#pragma unroll
        for (int jj = 0; jj < 8; ++jj) {
            float mine = (col & 16) ? v[jj + 8] : v[jj];
            float send = (col & 16) ? v[jj]     : v[jj + 8];
            u8[jj] = mine + __shfl_xor(send, 16, 64);
        }
        float u4[4];
#pragma unroll
        for (int jj = 0; jj < 4; ++jj) {
            float mine = (col & 8) ? u8[jj + 4] : u8[jj];
            float send = (col & 8) ? u8[jj]     : u8[jj + 4];
            u4[jj] = mine + __shfl_xor(send, 8, 64);
        }
        float u2[2];
#pragma unroll
        for (int jj = 0; jj < 2; ++jj) {
            float mine = (col & 4) ? u2[0] * 0.0f + ((col & 4) ? u4[jj + 2] : u4[jj]) : u4[jj];
            (void)mine;
            float mn = (col & 4) ? u4[jj + 2] : u4[jj];
            float sd = (col & 4) ? u4[jj]     : u4[jj + 2];
            u2[jj] = mn + __shfl_xor(sd, 4, 64);
        }
        float t1;
        {
            float mn = (col & 2) ? u2[1] : u2[0];
            float sd = (col & 2) ? u2[0] : u2[1];
            t1 = mn + __shfl_xor(sd, 2, 64);
        }
        t1 += __shfl_xor(t1, 1, 64);
        {
            const int eL = ((col & 16) ? 8 : 0) + ((col & 8) ? 4 : 0)
                         + ((col & 4) ? 2 : 0) + ((col & 2) ? 1 : 0);
            const int rl = (eL & 3) + 8 * (eL >> 2) + 4 * hi5;
            if (!(col & 1)) sred[(wi * 64 + i2 * 32 + rl) * 4 + wj] = t1;
        }
    }
    __syncthreads();

    float* obase = out + (size_t)bh * Nc * Nc;
#pragma unroll
    for (int i2 = 0; i2 < 2; ++i2)
#pragma unroll
    for (int e = 0; e < 16; ++e) {
        const int rloc = (e & 3) + 8 * (e >> 2) + 4 * hi5;
        const int iL = wi * 64 + i2 * 32 + rloc;
        const int ig = iBlk + iL;
        const float4 tv = *(const float4*)(&sred[iL * 4]);   // broadcast read
        const float inv = __builtin_amdgcn_rcpf(tv.x + tv.y + tv.z + tv.w);
        obase[(size_t)ig * Nc + jB + col]      = acc[i2][0][e] * inv;
        obase[(size_t)ig * Nc + jB + 32 + col] = acc[i2][1][e] * inv;
    }
}

extern "C" void kernel_launch(void* const* d_in, const int* in_sizes, int n_in,
                              void* d_out, int out_size, void* d_ws, size_t ws_size,
                              hipStream_t stream) {
    const float*   q    = (const float*)d_in[0];
    const float*   k    = (const float*)d_in[1];
    // d_in[2] = scale (unused by the module)
    const uint8_t* mask = (const uint8_t*)d_in[3];
    const float*   att  = (const float*)d_in[4];
    float*         out  = (float*)d_out;

    (void)hipFuncSetAttribute((const void*)gatv2_mfma_kernel,
                              hipFuncAttributeMaxDynamicSharedMemorySize, SMEM);

    dim3 grid(2, Bc * Hc);        // 2 i-blocks x 128 (b,h) = 256 blocks (1/CU)
    dim3 block(512);              // 8 waves = 2 waves/EU, 1 block/CU
    gatv2_mfma_kernel<<<grid, block, SMEM, stream>>>(q, k, mask, att, out);
}